// Round 9
// baseline (1177.179 us; speedup 1.0000x reference)
//
#include <hip/hip_runtime.h>

#define HH 32
#define LOG2E 1.44269504088896340736f
#define KCH 16   // TF pipeline chunk length (steps per ring half)

typedef float v2f __attribute__((ext_vector_type(2)));

// DPP: quad_perm broadcasts (gate q = lane&3) and row rotates (16-lane rows)
#define DPPF(v, ctrl) \
    __int_as_float(__builtin_amdgcn_update_dpp(0, __float_as_int(v), (ctrl), 0xF, 0xF, true))
#define QP_B0 0x00   // [0,0,0,0] -> gate i to all quad lanes
#define QP_B1 0x55   // [1,1,1,1] -> gate f
#define QP_B2 0xAA   // [2,2,2,2] -> gate g
#define QP_B3 0xFF   // [3,3,3,3] -> gate o
#define DPP_ROR4  0x124
#define DPP_ROR8  0x128
#define SWZ(v, pat) __int_as_float(__builtin_amdgcn_ds_swizzle(__float_as_int(v), (pat)))

__device__ __forceinline__ float hw_exp2(float x) {
    float r; asm("v_exp_f32 %0, %1" : "=v"(r) : "v"(x)); return r;
}
__device__ __forceinline__ float sigm_e(float z, float e) {
    return __builtin_amdgcn_rcpf(1.0f + hw_exp2(z * e));
}
__device__ __forceinline__ v2f pk_fma(v2f a, v2f b, v2f c) {
    return __builtin_elementwise_fma(a, b, c);   // v_pk_fma_f32
}
// LDS-only barrier: drain lgkmcnt (ds_write visibility), then the BUILTIN
// s_barrier (compiler-visible convergent barrier). Unlike __syncthreads(),
// no s_waitcnt vmcnt(0): outstanding HBM stores stay in flight across it
// (verified pattern: 8-phase GEMM template, learn_hip m194-m201).
__device__ __forceinline__ void wave_barrier() {
    asm volatile("s_waitcnt lgkmcnt(0)" ::: "memory");
    __builtin_amdgcn_s_barrier();
}
__device__ __forceinline__ void load_bc(const float* p, v2f* d) {
#pragma unroll
    for (int r = 0; r < 8; ++r) {                // 8x ds_read_b128 broadcast (conflict-free)
        float4 v = ((const float4*)p)[r];
        d[2*r]   = (v2f){v.x, v.y};
        d[2*r+1] = (v2f){v.z, v.w};
    }
}
// TF output path: full cross-lane sum
__device__ __forceinline__ float out_reduce(float p) {
    p += DPPF(p, DPP_ROR4);
    p += DPPF(p, DPP_ROR8);
    p += SWZ(p, 0x401F);             // xor16
    p += __shfl_xor(p, 32, 64);
    return p;
}

// 2-row (A,B) dot over 16 v2f weight regs; ACC=false starts with pk_mul
template<bool ACC>
__device__ __forceinline__ void dot2(const v2f* hv, const v2f* mA, const v2f* mB,
                                     v2f& P0, v2f& P1, v2f& P2, v2f& P3) {
    if (ACC) {
        P0 = pk_fma(hv[0], mA[0], P0); P1 = pk_fma(hv[1], mA[1], P1);
        P2 = pk_fma(hv[0], mB[0], P2); P3 = pk_fma(hv[1], mB[1], P3);
    } else {
        P0 = hv[0] * mA[0]; P1 = hv[1] * mA[1];
        P2 = hv[0] * mB[0]; P3 = hv[1] * mB[1];
    }
#pragma unroll
    for (int r = 2; r < 16; r += 2) {
        P0 = pk_fma(hv[r],   mA[r],   P0);
        P1 = pk_fma(hv[r+1], mA[r+1], P1);
        P2 = pk_fma(hv[r],   mB[r],   P2);
        P3 = pk_fma(hv[r+1], mB[r+1], P3);
    }
}

__device__ __forceinline__ void gate_hc(float zA, float zB, float es, float mm, float cc,
                                        float& cA, float& cB, float& hA, float& hB) {
    float acA = fmaf(mm, sigm_e(zA, es), cc);
    float acB = fmaf(mm, sigm_e(zB, es), cc);
    float iA = DPPF(acA, QP_B0), fA = DPPF(acA, QP_B1);
    float gA = DPPF(acA, QP_B2), oA = DPPF(acA, QP_B3);
    float iB = DPPF(acB, QP_B0), fB = DPPF(acB, QP_B1);
    float gB = DPPF(acB, QP_B2), oB = DPPF(acB, QP_B3);
    cA = fmaf(fA, cA, iA * gA);
    cB = fmaf(fB, cB, iB * gB);
    hA = oA * fmaf(2.0f, sigm_e(cA, -2.0f * LOG2E), -1.0f);
    hB = oB * fmaf(2.0f, sigm_e(cB, -2.0f * LOG2E), -1.0f);
}

// Layout (both waves): q=lane&3 (gate 0=i 1=f 2=g 3=o), ch=lane>>2 (0..15).
// Lane owns rows rowA=(q<<5)|ch and rowB=(q<<5)|(ch+16).
// TF: w0 = cell1 + Wih2·h1 partial dot (zring); w1 = cell2 + Whh2 dot + output.
// AR: 2-wave, 2 LDS-only barriers/step; outputs buffered per-lane in a register,
// flushed as one coalesced 64-wide store per 64 steps (no per-step HBM store
// on the chain, no vmcnt drain at any barrier).
__global__ __launch_bounds__(128, 2)
void lstm_seq_kernel(const float* __restrict__ input,
                     const float* __restrict__ W_ih1, const float* __restrict__ W_hh1,
                     const float* __restrict__ b_ih1, const float* __restrict__ b_hh1,
                     const float* __restrict__ W_ih2, const float* __restrict__ W_hh2,
                     const float* __restrict__ b_ih2, const float* __restrict__ b_hh2,
                     const float* __restrict__ W_lin, const float* __restrict__ b_lin,
                     float* __restrict__ out, int T, int total)
{
    const int b    = blockIdx.x;     // one block (2 waves) per batch element
    const int tid  = threadIdx.x;
    const int w    = tid >> 6;       // wave0 = cell1 (+ih2 dot), wave1 = cell2 (+TF out)
    const int lane = tid & 63;
    const int q    = lane & 3;
    const int ch   = lane >> 2;      // 0..15
    const int rowA = (q << 5) | ch;
    const int rowB = (q << 5) | (ch + 16);
    const int zidx = (q << 4) | ch;  // 0..63; 2 lanes/bank -> conflict-free

    __shared__ __align__(16) float zring[2 * KCH * 128]; // Wih2·h1(t) row partials
    __shared__ __align__(16) float h1self[HH];           // w0 TF self-roundtrip
    __shared__ __align__(16) float h1x[HH];              // AR h1 exchange
    __shared__ __align__(16) float h2s[HH];              // w1 h2 self-roundtrip / AR feedback

    const bool  isg = (q == 2);
    const float es  = isg ? (-2.0f * LOG2E) : (-LOG2E);
    const float mm  = isg ? 2.0f : 1.0f;
    const float cc  = isg ? -1.0f : 0.0f;

    // ---- per-wave weights ----
    // w0: m1=Whh1 rows, m2=Wih2 rows (TF partial dot). w1: m1=Wih2 rows, m2=Whh2 rows.
    v2f m1A[16], m1B[16], m2A[16], m2B[16];
    float wxA = 0.f, wxB = 0.f, bA, bB, blin;
    const float wlA = W_lin[ch], wlB = W_lin[ch + 16];
    if (w == 0) {
        const v2f* pA = (const v2f*)(W_hh1 + rowA * HH);
        const v2f* pB = (const v2f*)(W_hh1 + rowB * HH);
        const v2f* qA = (const v2f*)(W_ih2 + rowA * HH);
        const v2f* qB = (const v2f*)(W_ih2 + rowB * HH);
#pragma unroll
        for (int r = 0; r < 16; ++r) { m1A[r] = pA[r]; m1B[r] = pB[r];
                                       m2A[r] = qA[r]; m2B[r] = qB[r]; }
        wxA = W_ih1[rowA]; wxB = W_ih1[rowB];
        bA  = b_ih1[rowA] + b_hh1[rowA];
        bB  = b_ih1[rowB] + b_hh1[rowB];
    } else {
        const v2f* pA = (const v2f*)(W_ih2 + rowA * HH);
        const v2f* pB = (const v2f*)(W_ih2 + rowB * HH);
        const v2f* qA = (const v2f*)(W_hh2 + rowA * HH);
        const v2f* qB = (const v2f*)(W_hh2 + rowB * HH);
#pragma unroll
        for (int r = 0; r < 16; ++r) { m1A[r] = pA[r]; m1B[r] = pB[r];
                                       m2A[r] = qA[r]; m2B[r] = qB[r]; }
        bA  = b_ih2[rowA] + b_hh2[rowA];
        bB  = b_ih2[rowB] + b_hh2[rowB];
    }
    blin = b_lin[0];

    float cA = 0.f, cB = 0.f;        // c1 (wave0) / c2 (wave1)
    // carried dots: w0: Whh1·h1(t-1); w1: Whh2·h2(t-1)
    v2f p0 = {0.f,0.f}, p1 = {0.f,0.f}, p2 = {0.f,0.f}, p3 = {0.f,0.f};

    const float* __restrict__ inp  = input + (size_t)b * T;
    float* __restrict__       outp = out   + (size_t)b * total;

    // ================= Teacher-forced phase: chunk pipeline, rebalanced ==========
    if (w == 0) {
        int t = 0;
        float xcur = inp[0];
        for (int cb = 0; t < T; ++cb) {
            float* zbuf = zring + (cb & 1) * (KCH * 128);
            int S = T - t; if (S > KCH) S = KCH;
            for (int s = 0; s < S; ++s, ++t) {
                float x = xcur;
                int tn = t + 1;
                xcur = inp[tn < T ? tn : 0];            // prefetch, off-path
                v2f tA = p0 + p1, tB = p2 + p3;
                float z1A = fmaf(x, wxA, bA + tA.x + tA.y);
                float z1B = fmaf(x, wxB, bB + tB.x + tB.y);
                float hA, hB;
                gate_hc(z1A, z1B, es, mm, cc, cA, cB, hA, hB);
                if (q == 0) { h1self[ch] = hA; h1self[ch + 16] = hB; }
                v2f hv[16]; load_bc(h1self, hv);         // same-wave round trip
                dot2<false>(hv, m1A, m1B, p0, p1, p2, p3);   // Whh1·h1(t) carry
                v2f s0, s1, s2, s3;
                dot2<false>(hv, m2A, m2B, s0, s1, s2, s3);   // Wih2·h1(t) for w1
                v2f uA = s0 + s1, uB = s2 + s3;
                float* zs = zbuf + s * 128;
                zs[zidx]      = uA.x + uA.y;             // 2 lanes/bank: conflict-free
                zs[zidx + 64] = uB.x + uB.y;
            }
            wave_barrier();           // chunk (zring half) published
        }
        wave_barrier();               // match consumer
    } else {
        wave_barrier();               // wait for chunk 0
        int t = 0;
        for (int cb = 0; t < T; ++cb) {
            const float* zbuf = zring + (cb & 1) * (KCH * 128);
            int S = T - t; if (S > KCH) S = KCH;
            for (int s = 0; s < S; ++s, ++t) {
                const float* zs = zbuf + s * 128;
                float zihA = zs[zidx], zihB = zs[zidx + 64];
                v2f tA = p0 + p1, tB = p2 + p3;
                float z2A = bA + zihA + tA.x + tA.y;     // bias + Wih2·h1 + Whh2·h2
                float z2B = bB + zihB + tB.x + tB.y;
                float hA, hB;
                gate_hc(z2A, z2B, es, mm, cc, cA, cB, hA, hB);
                if (q == 0) { h2s[ch] = hA; h2s[ch + 16] = hB; }
                v2f gv[16]; load_bc(h2s, gv);            // same-wave round trip
                dot2<false>(gv, m2A, m2B, p0, p1, p2, p3);   // Whh2·h2(t) carry
                float pr = fmaf(hA, wlA, hB * wlB);
                float ov = out_reduce(pr) + blin;
                if (lane == 0) outp[t] = ov;             // stays in flight (no vmcnt drain)
            }
            wave_barrier();
        }
    }

    // ================= Autoregressive: 2 LDS-only barriers/step, reg-buffered out =
    // w0 recomputes x(t) = Wlin·h2(t-1)+b per-lane from the h2s broadcast.
    v2f wl[16];
    if (w == 0) {                     // m2 (Wih2 copy) dead after TF -> RA reuses
        const v2f* wp = (const v2f*)W_lin;
#pragma unroll
        for (int r = 0; r < 16; ++r) wl[r] = wp[r];
    }
    float obuf = 0.f;                 // rotating per-lane output buffer (w0)
    for (int t = T; t < total; ++t) {
        wave_barrier();                         // BX: h2s(t-1) visible, h1x WAR safe
        if (w == 0) {
            v2f gv[16]; load_bc(h2s, gv);
            v2f oa = gv[0] * wl[0], ob = gv[1] * wl[1];
#pragma unroll
            for (int r = 2; r < 16; r += 2) { oa = pk_fma(gv[r],   wl[r],   oa);
                                              ob = pk_fma(gv[r+1], wl[r+1], ob); }
            float xo = (oa.x + oa.y) + (ob.x + ob.y) + blin;   // = out(t-1)
            if (t > T) {                        // outp[T-1] was written by TF
                int oi = t - 1 - T;             // 0-based AR output index
                obuf = (lane == (oi & 63)) ? xo : obuf;
                if ((oi & 63) == 63)            // coalesced 64-wide flush
                    outp[T + (oi & ~63) + lane] = obuf;
            }
            v2f tA = p0 + p1, tB = p2 + p3;
            float z1A = fmaf(xo, wxA, bA + tA.x + tA.y);
            float z1B = fmaf(xo, wxB, bB + tB.x + tB.y);
            float hA, hB;
            gate_hc(z1A, z1B, es, mm, cc, cA, cB, hA, hB);
            if (q == 0) { h1x[ch] = hA; h1x[ch + 16] = hB; }
        } else {
            v2f gv[16]; load_bc(h2s, gv);       // own write from prev step
            dot2<false>(gv, m2A, m2B, p0, p1, p2, p3);   // refresh Whh2·h2 carry
        }
        wave_barrier();                         // BH: h1x visible
        if (w == 0) {
            v2f hv[16]; load_bc(h1x, hv);       // next z1 carry (shadow)
            dot2<false>(hv, m1A, m1B, p0, p1, p2, p3);
        } else {
            v2f hv[16]; load_bc(h1x, hv);
            dot2<true>(hv, m1A, m1B, p0, p1, p2, p3);    // in place: p dead after z2
            v2f tA = p0 + p1, tB = p2 + p3;
            float z2A = bA + tA.x + tA.y;
            float z2B = bB + tB.x + tB.y;
            float hA, hB;
            gate_hc(z2A, z2B, es, mm, cc, cA, cB, hA, hB);
            if (q == 0) { h2s[ch] = hA; h2s[ch + 16] = hB; }
        }
    }
    // tail: out(total-1) = Wlin·h2(total-1)+b, then flush the partial block
    wave_barrier();
    if (w == 0) {
        v2f gv[16]; load_bc(h2s, gv);
        v2f oa = gv[0] * wl[0], ob = gv[1] * wl[1];
#pragma unroll
        for (int r = 2; r < 16; r += 2) { oa = pk_fma(gv[r],   wl[r],   oa);
                                          ob = pk_fma(gv[r+1], wl[r+1], ob); }
        float xo = (oa.x + oa.y) + (ob.x + ob.y) + blin;
        int oi = total - 1 - T;                 // tail output index
        obuf = (lane == (oi & 63)) ? xo : obuf;
        if (lane <= (oi & 63))
            outp[T + (oi & ~63) + lane] = obuf;
    }
}

extern "C" void kernel_launch(void* const* d_in, const int* in_sizes, int n_in,
                              void* d_out, int out_size, void* d_ws, size_t ws_size,
                              hipStream_t stream) {
    const int B = 1024;                 // fixed by the source module
    const int T = in_sizes[0] / B;      // 999
    const int total = out_size / B;     // T + future = 1999

    lstm_seq_kernel<<<dim3(B), dim3(128), 0, stream>>>(
        (const float*)d_in[0],
        (const float*)d_in[1], (const float*)d_in[2],
        (const float*)d_in[3], (const float*)d_in[4],
        (const float*)d_in[5], (const float*)d_in[6],
        (const float*)d_in[7], (const float*)d_in[8],
        (const float*)d_in[9], (const float*)d_in[10],
        (float*)d_out, T, total);
}